// Round 2
// baseline (13981.685 us; speedup 1.0000x reference)
//
#include <hip/hip_runtime.h>
#include <hip/hip_bf16.h>

#define NPTS 16384
#define MCENT 4096
#define BCLD 2
#define FDIM 32
#define H1DIM 64
#define CODIM 128
#define KNBR 64
// largest fp32 <= 0.04 (float64) == fp32(0.04f) == 0.039999999105930328
#define R2CUT 0.04f

// Exact (numpy-order, contraction-free) squared distance: ((dx*dx+dy*dy)+dz*dz)
__device__ __forceinline__ float d2e(float ax, float ay, float az,
                                     float bx, float by, float bz) {
  float dx = __fsub_rn(ax, bx);
  float dy = __fsub_rn(ay, by);
  float dz = __fsub_rn(az, bz);
  return __fadd_rn(__fadd_rn(__fmul_rn(dx, dx), __fmul_rn(dy, dy)), __fmul_rn(dz, dz));
}

// ---------------- Kernel 1: farthest point sampling (1 block per cloud) ----
// 512 threads x 32 pts. Points are counting-sorted by 8x8x8 grid cell so each
// thread's chunk is spatially compact; a chunk whose bbox lower-bound distance
// to the new centroid exceeds its cached max-d is provably unchanged (margin
// 0.999 >> fp rounding), so both the d-update and the argmax recompute are
// skipped. One barrier/iter via parity-double-buffered per-wave winner slots.
__global__ __launch_bounds__(512) void fps_kernel(const float* __restrict__ pos,
                                                  int* __restrict__ fps_idx,
                                                  float4* __restrict__ ws_sorted) {
  const int b = blockIdx.x;
  const float* P = pos + (size_t)b * NPTS * 3;
  float4* S = ws_sorted + (size_t)b * NPTS;
  const int tid = threadIdx.x;
  const int lane = tid & 63;
  const int wave = tid >> 6;  // 0..7

  __shared__ int hist[512];
  __shared__ int offs[512];
  __shared__ unsigned long long skey[2][8];
  __shared__ float4 spos[2][8];

  // ---- phase A: counting sort by grid cell into ws_sorted (global) ----
  if (tid < 512) hist[tid] = 0;
  __syncthreads();
#pragma unroll 4
  for (int j = 0; j < 32; ++j) {
    int i = tid + j * 512;
    float x = P[3 * i + 0], y = P[3 * i + 1], z = P[3 * i + 2];
    int cx = min(7, (int)(x * 8.0f));
    int cy = min(7, (int)(y * 8.0f));
    int cz = min(7, (int)(z * 8.0f));
    atomicAdd(&hist[(cx << 6) | (cy << 3) | cz], 1);
  }
  __syncthreads();
  if (tid < 64) {  // wave 0: exclusive scan of 512 cells
    int base = tid * 8;
    int loc[8];
    int run = 0;
#pragma unroll
    for (int k = 0; k < 8; ++k) { loc[k] = run; run += hist[base + k]; }
    int inc = run;
#pragma unroll
    for (int off = 1; off < 64; off <<= 1) {
      int o = __shfl_up(inc, off);
      if (tid >= off) inc += o;
    }
    int ex = inc - run;
#pragma unroll
    for (int k = 0; k < 8; ++k) offs[base + k] = ex + loc[k];
  }
  __syncthreads();
#pragma unroll 4
  for (int j = 0; j < 32; ++j) {
    int i = tid + j * 512;
    float x = P[3 * i + 0], y = P[3 * i + 1], z = P[3 * i + 2];
    int cx = min(7, (int)(x * 8.0f));
    int cy = min(7, (int)(y * 8.0f));
    int cz = min(7, (int)(z * 8.0f));
    int p = atomicAdd(&offs[(cx << 6) | (cy << 3) | cz], 1);
    S[p] = make_float4(x, y, z, __int_as_float(i));
  }
  __syncthreads();  // global S writes drained (vmcnt(0) before barrier)

  // ---- phase B: load chunk, init d vs original point 0, bbox ----
  float px[32], py[32], pz[32], d[32];
  int oidx[32];
  const float x0 = P[0], y0 = P[1], z0 = P[2];
  float bxm, bxM, bym, byM, bzm, bzM;
#pragma unroll
  for (int j = 0; j < 32; ++j) {
    float4 v = S[tid * 32 + j];
    px[j] = v.x; py[j] = v.y; pz[j] = v.z;
    oidx[j] = __float_as_int(v.w);
    d[j] = d2e(v.x, v.y, v.z, x0, y0, z0);
    if (j == 0) {
      bxm = v.x; bxM = v.x; bym = v.y; byM = v.y; bzm = v.z; bzM = v.z;
    } else {
      bxm = fminf(bxm, v.x); bxM = fmaxf(bxM, v.x);
      bym = fminf(bym, v.y); byM = fmaxf(byM, v.y);
      bzm = fminf(bzm, v.z); bzM = fmaxf(bzM, v.z);
    }
  }

  // local argmax (tie -> lowest original index)
  float bd = d[0]; int bi = oidx[0];
  float bx = px[0], by = py[0], bz = pz[0];
#pragma unroll
  for (int j = 1; j < 32; ++j) {
    bool g = (d[j] > bd) || (d[j] == bd && oidx[j] < bi);
    if (g) { bd = d[j]; bi = oidx[j]; bx = px[j]; by = py[j]; bz = pz[j]; }
  }
  unsigned long long key = ((unsigned long long)__float_as_uint(bd) << 32)
                         | (unsigned long long)(unsigned)(~(unsigned)bi);

  if (tid == 0) fps_idx[b * MCENT] = 0;

  bool wdirty = true;
  bool owner = false;
  unsigned long long wk = 0;

  for (int m = 1; m < MCENT; ++m) {
    const int bufp = m & 1;
    if (wdirty) {  // recompute wave winner + owner lane
      wk = key;
#pragma unroll
      for (int off = 32; off >= 1; off >>= 1) {
        unsigned long long o = __shfl_xor(wk, off);
        if (o > wk) wk = o;
      }
      unsigned long long mask = __ballot(key == wk);
      owner = (lane == (int)__ffsll(mask) - 1);
    }
    if (owner) {  // always republish (parity buffer alternates)
      skey[bufp][wave] = wk;
      spos[bufp][wave] = make_float4(bx, by, bz, 0.0f);
    }
    __syncthreads();

    // cross-wave reduce: each 8-lane group reads the 8 slots, butterflies
    unsigned long long k8 = skey[bufp][lane & 7];
    int wv = lane & 7;
#pragma unroll
    for (int off = 1; off <= 4; off <<= 1) {
      unsigned long long ok = __shfl_xor(k8, off);
      int ov = __shfl_xor(wv, off);
      if (ok > k8) { k8 = ok; wv = ov; }
    }
    if (tid == 0) fps_idx[b * MCENT + m] = (int)(~(unsigned)k8);
    float4 wp = spos[bufp][wv];  // broadcast read

    // prune: lower-bound distance from winner to chunk bbox
    float ex = fmaxf(fmaxf(bxm - wp.x, wp.x - bxM), 0.0f);
    float ey = fmaxf(fmaxf(bym - wp.y, wp.y - byM), 0.0f);
    float ez = fmaxf(fmaxf(bzm - wp.z, wp.z - bzM), 0.0f);
    float lb = (ex * ex + ey * ey + ez * ez) * 0.999f;
    bool dirty = lb < bd;
    if (dirty) {
#pragma unroll
      for (int j = 0; j < 32; ++j)
        d[j] = fminf(d[j], d2e(px[j], py[j], pz[j], wp.x, wp.y, wp.z));
      bd = d[0]; bi = oidx[0]; bx = px[0]; by = py[0]; bz = pz[0];
#pragma unroll
      for (int j = 1; j < 32; ++j) {
        bool g = (d[j] > bd) || (d[j] == bd && oidx[j] < bi);
        if (g) { bd = d[j]; bi = oidx[j]; bx = px[j]; by = py[j]; bz = pz[j]; }
      }
      key = ((unsigned long long)__float_as_uint(bd) << 32)
          | (unsigned long long)(unsigned)(~(unsigned)bi);
    }
    wdirty = (__ballot(dirty) != 0ULL);
  }
}

// ------------- Kernel 2: ball query + K-smallest selection (1 wave/centroid) --
__global__ __launch_bounds__(256) void ballq_kernel(const float* __restrict__ pos,
                                                    const int* __restrict__ fps_idx,
                                                    int* __restrict__ nbr,
                                                    float* __restrict__ out_pc,
                                                    float* __restrict__ out_batch) {
  const int wave = threadIdx.x >> 6;
  const int lane = threadIdx.x & 63;
  const int c = blockIdx.x * 4 + wave;   // global centroid id
  const int b = c >> 12;                 // 4096 centroids per cloud
  const float* P = pos + (size_t)b * NPTS * 3;

  const int ci = fps_idx[c];
  const float cx = P[3 * ci + 0];
  const float cy = P[3 * ci + 1];
  const float cz = P[3 * ci + 2];
  if (lane == 0) {
    out_pc[3 * c + 0] = cx;
    out_pc[3 * c + 1] = cy;
    out_pc[3 * c + 2] = cz;
    out_batch[c] = (float)b;
  }

  __shared__ unsigned long long list[4][1024];
  __shared__ int cnt[4];
  if (lane == 0) cnt[wave] = 0;

  for (int i = lane; i < NPTS; i += 64) {
    const float qx = P[3 * i + 0];
    const float qy = P[3 * i + 1];
    const float qz = P[3 * i + 2];
    const float dd = d2e(cx, cy, cz, qx, qy, qz);
    if (dd <= R2CUT) {
      int p = atomicAdd(&cnt[wave], 1);
      if (p < 1024)
        list[wave][p] = ((unsigned long long)__float_as_uint(dd) << 32)
                      | (unsigned long long)(unsigned)i;
    }
  }
  __syncthreads();

  int n = cnt[wave];
  if (n > 1024) n = 1024;

  unsigned long long loc[16];
#pragma unroll
  for (int k = 0; k < 16; ++k) {
    int i = lane + k * 64;
    loc[k] = (i < n) ? list[wave][i] : ~0ULL;
  }
  unsigned long long mv = loc[0];
#pragma unroll
  for (int k = 1; k < 16; ++k)
    if (loc[k] < mv) mv = loc[k];

  int myout = -1;
  for (int s = 0; s < 64; ++s) {
    unsigned long long wmin = mv;
#pragma unroll
    for (int off = 32; off >= 1; off >>= 1) {
      unsigned long long o = __shfl_xor(wmin, off);
      if (o < wmin) wmin = o;
    }
    if (lane == s) myout = (wmin == ~0ULL) ? -1 : (int)(unsigned)wmin;
    if (mv == wmin && wmin != ~0ULL) {
#pragma unroll
      for (int k = 0; k < 16; ++k)
        if (loc[k] == wmin) loc[k] = ~0ULL;
      mv = loc[0];
#pragma unroll
      for (int k = 1; k < 16; ++k)
        if (loc[k] < mv) mv = loc[k];
    }
  }
  nbr[c * KNBR + lane] = myout;
}

// ------------- Kernel 3: MLP (35->64 relu ->128) + masked max-pool ----------
__global__ __launch_bounds__(256) void mlp_kernel(const float* __restrict__ pos,
                                                  const float* __restrict__ x,
                                                  const int* __restrict__ fps_idx,
                                                  const int* __restrict__ nbr,
                                                  const float* __restrict__ W1,
                                                  const float* __restrict__ b1,
                                                  const float* __restrict__ W2,
                                                  const float* __restrict__ b2,
                                                  float* __restrict__ out) {
  const int c = blockIdx.x;
  const int b = c >> 12;
  const float* P = pos + (size_t)b * NPTS * 3;
  const float* X = x + (size_t)b * NPTS * FDIM;

  __shared__ float W1s[35 * 64];
  __shared__ float W2s[64 * 128];
  __shared__ float b1s[64];
  __shared__ float b2s[128];
  __shared__ float h1s[64][64];
  __shared__ float pmax[2][128];
  __shared__ int validk[64];

  const int tid = threadIdx.x;
  for (int i = tid; i < 35 * 64; i += 256) W1s[i] = W1[i];
  for (int i = tid; i < 64 * 128; i += 256) W2s[i] = W2[i];
  if (tid < 64) b1s[tid] = b1[tid];
  else if (tid < 192) b2s[tid - 64] = b2[tid - 64];

  const int ci = fps_idx[c];
  const float c5x = P[3 * ci + 0] / 0.2f;  // faithful: pos_i / r
  const float c5y = P[3 * ci + 1] / 0.2f;
  const float c5z = P[3 * ci + 2] / 0.2f;

  const int k = tid >> 2, q = tid & 3;
  const int nk = nbr[c * KNBR + k];
  if (q == 0) validk[k] = (nk >= 0) ? 1 : 0;
  const int nkc = (nk < 0) ? 0 : nk;

  float msg[35];
  const float4* Xr = (const float4*)(X + (size_t)nkc * FDIM);
#pragma unroll
  for (int i4 = 0; i4 < 8; ++i4) {
    float4 v = Xr[i4];
    msg[i4 * 4 + 0] = v.x; msg[i4 * 4 + 1] = v.y;
    msg[i4 * 4 + 2] = v.z; msg[i4 * 4 + 3] = v.w;
  }
  msg[32] = P[3 * nkc + 0] - c5x;
  msg[33] = P[3 * nkc + 1] - c5y;
  msg[34] = P[3 * nkc + 2] - c5z;

  __syncthreads();

  float acc[16];
#pragma unroll
  for (int h = 0; h < 16; ++h) acc[h] = b1s[q * 16 + h];
#pragma unroll
  for (int i = 0; i < 35; ++i) {
    const float m = msg[i];
    const float4* wrow = (const float4*)&W1s[i * 64 + q * 16];
#pragma unroll
    for (int j4 = 0; j4 < 4; ++j4) {
      float4 w = wrow[j4];
      acc[j4 * 4 + 0] += m * w.x;
      acc[j4 * 4 + 1] += m * w.y;
      acc[j4 * 4 + 2] += m * w.z;
      acc[j4 * 4 + 3] += m * w.w;
    }
  }
#pragma unroll
  for (int h = 0; h < 16; ++h) h1s[k][q * 16 + h] = fmaxf(acc[h], 0.0f);
  __syncthreads();

  const int ch = tid & 127, half = tid >> 7;
  float w2r[64];
#pragma unroll
  for (int i = 0; i < 64; ++i) w2r[i] = W2s[i * 128 + ch];

  float mx = -INFINITY;
  for (int k2 = half * 32; k2 < half * 32 + 32; ++k2) {
    if (!validk[k2]) continue;
    float s = b2s[ch];
    const float4* hr = (const float4*)h1s[k2];
#pragma unroll
    for (int i4 = 0; i4 < 16; ++i4) {
      float4 h4 = hr[i4];
      s += h4.x * w2r[i4 * 4 + 0] + h4.y * w2r[i4 * 4 + 1]
         + h4.z * w2r[i4 * 4 + 2] + h4.w * w2r[i4 * 4 + 3];
    }
    mx = fmaxf(mx, s);
  }
  pmax[half][ch] = mx;
  __syncthreads();

  if (tid < 128) {
    float m2 = fmaxf(pmax[0][tid], pmax[1][tid]);
    out[(size_t)c * CODIM + tid] = (m2 > -INFINITY) ? m2 : 0.0f;
  }
}

extern "C" void kernel_launch(void* const* d_in, const int* in_sizes, int n_in,
                              void* d_out, int out_size, void* d_ws, size_t ws_size,
                              hipStream_t stream) {
  const float* x   = (const float*)d_in[0];
  const float* pos = (const float*)d_in[1];
  const float* W1  = (const float*)d_in[3];
  const float* b1  = (const float*)d_in[4];
  const float* W2  = (const float*)d_in[5];
  const float* b2  = (const float*)d_in[6];
  float* out = (float*)d_out;

  int* fps_idx = (int*)d_ws;                  // B*M ints = 32 KiB
  int* nbr     = (int*)d_ws + BCLD * MCENT;   // B*M*K ints = 2 MiB
  // fps scratch aliases the nbr region (fps completes before ballq writes nbr)
  float4* ws_sorted = (float4*)nbr;           // B*N float4 = 512 KiB

  float* out_pc    = out + (size_t)BCLD * MCENT * CODIM;
  float* out_batch = out_pc + (size_t)BCLD * MCENT * 3;

  hipLaunchKernelGGL(fps_kernel, dim3(BCLD), dim3(512), 0, stream, pos, fps_idx, ws_sorted);
  hipLaunchKernelGGL(ballq_kernel, dim3(BCLD * MCENT / 4), dim3(256), 0, stream,
                     pos, fps_idx, nbr, out_pc, out_batch);
  hipLaunchKernelGGL(mlp_kernel, dim3(BCLD * MCENT), dim3(256), 0, stream,
                     pos, x, fps_idx, nbr, W1, b1, W2, b2, out);
}

// Round 3
// 8229.134 us; speedup vs baseline: 1.6990x; 1.6990x over previous
//
#include <hip/hip_runtime.h>
#include <hip/hip_bf16.h>

#define NPTS 16384
#define MCENT 4096
#define BCLD 2
#define FDIM 32
#define H1DIM 64
#define CODIM 128
#define KNBR 64
// largest fp32 <= 0.04 (float64) == fp32(0.04f) == 0.039999999105930328
#define R2CUT 0.04f

// Exact (numpy-order, contraction-free) squared distance: ((dx*dx+dy*dy)+dz*dz)
__device__ __forceinline__ float d2e(float ax, float ay, float az,
                                     float bx, float by, float bz) {
  float dx = __fsub_rn(ax, bx);
  float dy = __fsub_rn(ay, by);
  float dz = __fsub_rn(az, bz);
  return __fadd_rn(__fadd_rn(__fmul_rn(dx, dx), __fmul_rn(dy, dy)), __fmul_rn(dz, dz));
}

// Lexicographic max over (bits, nidx) pairs via DPP (VALU pipe — no LDS).
// Identity (0,0) can never beat a real candidate (real nidx = ~oidx > 0).
#define DPP_LEXMAX_STEP(bb, nn, ctrl)                                          \
  do {                                                                         \
    unsigned _ob = (unsigned)__builtin_amdgcn_update_dpp(0, (int)(bb), ctrl,   \
                                                         0xf, 0xf, false);     \
    unsigned _on = (unsigned)__builtin_amdgcn_update_dpp(0, (int)(nn), ctrl,   \
                                                         0xf, 0xf, false);     \
    bool _t = (_ob > (bb)) || (_ob == (bb) && _on > (nn));                     \
    (bb) = _t ? _ob : (bb);                                                    \
    (nn) = _t ? _on : (nn);                                                    \
  } while (0)

__device__ __forceinline__ int rdlane(int v, int l) {
  return __builtin_amdgcn_readlane(v, l);
}
__device__ __forceinline__ float rdlanef(float v, int l) {
  return __int_as_float(__builtin_amdgcn_readlane(__float_as_int(v), l));
}

// ---------------- Kernel 1: farthest point sampling (1 block per cloud) ----
// 1024 threads x 16 pts (counting-sorted by 8x8x8 cell => spatially compact
// chunks). Per-chunk bbox prune skips provably-unchanged chunks (0.999 margin
// >> fp rounding). Reductions are DPP lexmax chains (VALU pipe) + readlane;
// cross-wave via 16 parity-double-buffered LDS slots; ONE barrier/iter; no
// global memory ops inside the loop (winners buffered in LDS).
__global__ __launch_bounds__(1024) void fps_kernel(const float* __restrict__ pos,
                                                   int* __restrict__ fps_idx,
                                                   float4* __restrict__ ws_sorted) {
  const int b = blockIdx.x;
  const float* P = pos + (size_t)b * NPTS * 3;
  float4* S = ws_sorted + (size_t)b * NPTS;
  const int tid = threadIdx.x;
  const int lane = tid & 63;
  const int wave = tid >> 6;  // 0..15

  __shared__ int hist[512];
  __shared__ int offs[512];
  __shared__ unsigned long long skey[2][16];
  __shared__ float spos[2][16][4];
  __shared__ int winners[MCENT];

  // ---- phase A: counting sort by grid cell into ws_sorted (global) ----
  if (tid < 512) hist[tid] = 0;
  __syncthreads();
#pragma unroll 4
  for (int j = 0; j < 16; ++j) {
    int i = tid + j * 1024;
    float x = P[3 * i + 0], y = P[3 * i + 1], z = P[3 * i + 2];
    int cx = min(7, (int)(x * 8.0f));
    int cy = min(7, (int)(y * 8.0f));
    int cz = min(7, (int)(z * 8.0f));
    atomicAdd(&hist[(cx << 6) | (cy << 3) | cz], 1);
  }
  __syncthreads();
  if (tid < 64) {  // wave 0: exclusive scan of 512 cells
    int base = tid * 8;
    int loc[8];
    int run = 0;
#pragma unroll
    for (int k = 0; k < 8; ++k) { loc[k] = run; run += hist[base + k]; }
    int inc = run;
#pragma unroll
    for (int off = 1; off < 64; off <<= 1) {
      int o = __shfl_up(inc, off);
      if (tid >= off) inc += o;
    }
    int ex = inc - run;
#pragma unroll
    for (int k = 0; k < 8; ++k) offs[base + k] = ex + loc[k];
  }
  __syncthreads();
#pragma unroll 4
  for (int j = 0; j < 16; ++j) {
    int i = tid + j * 1024;
    float x = P[3 * i + 0], y = P[3 * i + 1], z = P[3 * i + 2];
    int cx = min(7, (int)(x * 8.0f));
    int cy = min(7, (int)(y * 8.0f));
    int cz = min(7, (int)(z * 8.0f));
    int p = atomicAdd(&offs[(cx << 6) | (cy << 3) | cz], 1);
    S[p] = make_float4(x, y, z, __int_as_float(i));
  }
  __syncthreads();  // global S writes drained before re-read (validated in R2)

  // ---- phase B: load 16-pt chunk, init d vs original point 0, bbox, best ----
  float px[16], py[16], pz[16], d[16];
  int oidx[16];
  const float x0 = P[0], y0 = P[1], z0 = P[2];
  float bxm, bxM, bym, byM, bzm, bzM;
  unsigned tb = 0u, tn = 0u;           // thread-best (d bits, ~oidx)
  float tx = 0.f, ty = 0.f, tz = 0.f;  // thread-best position
#pragma unroll
  for (int j = 0; j < 16; ++j) {
    float4 v = S[tid * 16 + j];
    px[j] = v.x; py[j] = v.y; pz[j] = v.z;
    oidx[j] = __float_as_int(v.w);
    float dj = d2e(v.x, v.y, v.z, x0, y0, z0);
    d[j] = dj;
    if (j == 0) {
      bxm = v.x; bxM = v.x; bym = v.y; byM = v.y; bzm = v.z; bzM = v.z;
    } else {
      bxm = fminf(bxm, v.x); bxM = fmaxf(bxM, v.x);
      bym = fminf(bym, v.y); byM = fmaxf(byM, v.y);
      bzm = fminf(bzm, v.z); bzM = fmaxf(bzM, v.z);
    }
    unsigned db = __float_as_uint(dj);
    unsigned nj = ~(unsigned)oidx[j];
    bool t = (db > tb) || (db == tb && nj > tn);
    tb = t ? db : tb; tn = t ? nj : tn;
    tx = t ? v.x : tx; ty = t ? v.y : ty; tz = t ? v.z : tz;
  }

  if (tid == 0) winners[0] = 0;

  bool wavedirty = true;
  unsigned cwb = 0u, cwn = 0u;           // cached wave-winner key
  float cwx = 0.f, cwy = 0.f, cwz = 0.f; // cached wave-winner pos

  for (int m = 1; m < MCENT; ++m) {
    const int par = m & 1;

    if (wavedirty) {  // recompute wave winner via full-wave DPP lexmax
      unsigned bb = tb, nn = tn;
      DPP_LEXMAX_STEP(bb, nn, 0x111);  // row_shr:1
      DPP_LEXMAX_STEP(bb, nn, 0x112);  // row_shr:2
      DPP_LEXMAX_STEP(bb, nn, 0x114);  // row_shr:4
      DPP_LEXMAX_STEP(bb, nn, 0x118);  // row_shr:8
      DPP_LEXMAX_STEP(bb, nn, 0x142);  // row_bcast:15
      DPP_LEXMAX_STEP(bb, nn, 0x143);  // row_bcast:31
      cwb = (unsigned)rdlane((int)bb, 63);
      cwn = (unsigned)rdlane((int)nn, 63);
      unsigned long long own = __ballot(tb == cwb && tn == cwn);
      int ol = (int)__ffsll(own) - 1;  // unique: nidx carries a unique point id
      cwx = rdlanef(tx, ol);
      cwy = rdlanef(ty, ol);
      cwz = rdlanef(tz, ol);
    }
    if (lane == 0) {  // always republish (parity buffer alternates)
      skey[par][wave] = ((unsigned long long)cwb << 32) | (unsigned long long)cwn;
      spos[par][wave][0] = cwx;
      spos[par][wave][1] = cwy;
      spos[par][wave][2] = cwz;
    }
    __syncthreads();  // only lgkm traffic pending — cheap drain

    // cross-wave reduce: lanes 0..15 each take one slot, 4-step DPP lexmax
    unsigned rb, rn;
    unsigned sb0 = 0u, sn0 = 0u;
    {
      unsigned bb = 0u, nn = 0u;
      if (lane < 16) {
        unsigned long long kk = skey[par][lane];
        bb = (unsigned)(kk >> 32);
        nn = (unsigned)kk;
        sb0 = bb; sn0 = nn;
        DPP_LEXMAX_STEP(bb, nn, 0x111);
        DPP_LEXMAX_STEP(bb, nn, 0x112);
        DPP_LEXMAX_STEP(bb, nn, 0x114);
        DPP_LEXMAX_STEP(bb, nn, 0x118);
      }
      rb = (unsigned)rdlane((int)bb, 15);
      rn = (unsigned)rdlane((int)nn, 15);
    }
    unsigned long long wm = __ballot(lane < 16 && sb0 == rb && sn0 == rn);
    int ws = (int)__ffsll(wm) - 1;  // winning slot (wave) id — unique key
    float wx = spos[par][ws][0];    // uniform addr => LDS broadcast reads
    float wy = spos[par][ws][1];
    float wz = spos[par][ws][2];
    if (tid == 0) winners[m] = (int)(~rn);

    // prune: lower-bound distance from winner to chunk bbox
    float ex = fmaxf(fmaxf(bxm - wx, wx - bxM), 0.0f);
    float ey = fmaxf(fmaxf(bym - wy, wy - byM), 0.0f);
    float ez = fmaxf(fmaxf(bzm - wz, wz - bzM), 0.0f);
    float lb = (ex * ex + ey * ey + ez * ez) * 0.999f;
    bool mydirty = lb < __uint_as_float(tb);
    if (mydirty) {
      unsigned nb = 0u, nn2 = 0u;
      float nx = 0.f, ny = 0.f, nz = 0.f;
#pragma unroll
      for (int j = 0; j < 16; ++j) {
        float dj = fminf(d[j], d2e(px[j], py[j], pz[j], wx, wy, wz));
        d[j] = dj;
        unsigned db = __float_as_uint(dj);
        unsigned nj = ~(unsigned)oidx[j];
        bool t = (db > nb) || (db == nb && nj > nn2);
        nb = t ? db : nb; nn2 = t ? nj : nn2;
        nx = t ? px[j] : nx; ny = t ? py[j] : ny; nz = t ? pz[j] : nz;
      }
      tb = nb; tn = nn2; tx = nx; ty = ny; tz = nz;
    }
    wavedirty = (__ballot(mydirty) != 0ULL);
  }

  __syncthreads();
  for (int i = tid; i < MCENT; i += 1024) fps_idx[b * MCENT + i] = winners[i];
}

// ------------- Kernel 2: ball query + K-smallest selection (1 wave/centroid) --
__global__ __launch_bounds__(256) void ballq_kernel(const float* __restrict__ pos,
                                                    const int* __restrict__ fps_idx,
                                                    int* __restrict__ nbr,
                                                    float* __restrict__ out_pc,
                                                    float* __restrict__ out_batch) {
  const int wave = threadIdx.x >> 6;
  const int lane = threadIdx.x & 63;
  const int c = blockIdx.x * 4 + wave;   // global centroid id
  const int b = c >> 12;                 // 4096 centroids per cloud
  const float* P = pos + (size_t)b * NPTS * 3;

  const int ci = fps_idx[c];
  const float cx = P[3 * ci + 0];
  const float cy = P[3 * ci + 1];
  const float cz = P[3 * ci + 2];
  if (lane == 0) {
    out_pc[3 * c + 0] = cx;
    out_pc[3 * c + 1] = cy;
    out_pc[3 * c + 2] = cz;
    out_batch[c] = (float)b;
  }

  __shared__ unsigned long long list[4][1024];
  __shared__ int cnt[4];
  if (lane == 0) cnt[wave] = 0;

  for (int i = lane; i < NPTS; i += 64) {
    const float qx = P[3 * i + 0];
    const float qy = P[3 * i + 1];
    const float qz = P[3 * i + 2];
    const float dd = d2e(cx, cy, cz, qx, qy, qz);
    if (dd <= R2CUT) {
      int p = atomicAdd(&cnt[wave], 1);
      if (p < 1024)
        list[wave][p] = ((unsigned long long)__float_as_uint(dd) << 32)
                      | (unsigned long long)(unsigned)i;
    }
  }
  __syncthreads();

  int n = cnt[wave];
  if (n > 1024) n = 1024;

  unsigned long long loc[16];
#pragma unroll
  for (int k = 0; k < 16; ++k) {
    int i = lane + k * 64;
    loc[k] = (i < n) ? list[wave][i] : ~0ULL;
  }
  unsigned long long mv = loc[0];
#pragma unroll
  for (int k = 1; k < 16; ++k)
    if (loc[k] < mv) mv = loc[k];

  int myout = -1;
  for (int s = 0; s < 64; ++s) {
    unsigned long long wmin = mv;
#pragma unroll
    for (int off = 32; off >= 1; off >>= 1) {
      unsigned long long o = __shfl_xor(wmin, off);
      if (o < wmin) wmin = o;
    }
    if (lane == s) myout = (wmin == ~0ULL) ? -1 : (int)(unsigned)wmin;
    if (mv == wmin && wmin != ~0ULL) {
#pragma unroll
      for (int k = 0; k < 16; ++k)
        if (loc[k] == wmin) loc[k] = ~0ULL;
      mv = loc[0];
#pragma unroll
      for (int k = 1; k < 16; ++k)
        if (loc[k] < mv) mv = loc[k];
    }
  }
  nbr[c * KNBR + lane] = myout;
}

// ------------- Kernel 3: MLP (35->64 relu ->128) + masked max-pool ----------
__global__ __launch_bounds__(256) void mlp_kernel(const float* __restrict__ pos,
                                                  const float* __restrict__ x,
                                                  const int* __restrict__ fps_idx,
                                                  const int* __restrict__ nbr,
                                                  const float* __restrict__ W1,
                                                  const float* __restrict__ b1,
                                                  const float* __restrict__ W2,
                                                  const float* __restrict__ b2,
                                                  float* __restrict__ out) {
  const int c = blockIdx.x;
  const int b = c >> 12;
  const float* P = pos + (size_t)b * NPTS * 3;
  const float* X = x + (size_t)b * NPTS * FDIM;

  __shared__ float W1s[35 * 64];
  __shared__ float W2s[64 * 128];
  __shared__ float b1s[64];
  __shared__ float b2s[128];
  __shared__ float h1s[64][64];
  __shared__ float pmax[2][128];
  __shared__ int validk[64];

  const int tid = threadIdx.x;
  for (int i = tid; i < 35 * 64; i += 256) W1s[i] = W1[i];
  for (int i = tid; i < 64 * 128; i += 256) W2s[i] = W2[i];
  if (tid < 64) b1s[tid] = b1[tid];
  else if (tid < 192) b2s[tid - 64] = b2[tid - 64];

  const int ci = fps_idx[c];
  const float c5x = P[3 * ci + 0] / 0.2f;  // faithful: pos_i / r
  const float c5y = P[3 * ci + 1] / 0.2f;
  const float c5z = P[3 * ci + 2] / 0.2f;

  const int k = tid >> 2, q = tid & 3;
  const int nk = nbr[c * KNBR + k];
  if (q == 0) validk[k] = (nk >= 0) ? 1 : 0;
  const int nkc = (nk < 0) ? 0 : nk;

  float msg[35];
  const float4* Xr = (const float4*)(X + (size_t)nkc * FDIM);
#pragma unroll
  for (int i4 = 0; i4 < 8; ++i4) {
    float4 v = Xr[i4];
    msg[i4 * 4 + 0] = v.x; msg[i4 * 4 + 1] = v.y;
    msg[i4 * 4 + 2] = v.z; msg[i4 * 4 + 3] = v.w;
  }
  msg[32] = P[3 * nkc + 0] - c5x;
  msg[33] = P[3 * nkc + 1] - c5y;
  msg[34] = P[3 * nkc + 2] - c5z;

  __syncthreads();

  float acc[16];
#pragma unroll
  for (int h = 0; h < 16; ++h) acc[h] = b1s[q * 16 + h];
#pragma unroll
  for (int i = 0; i < 35; ++i) {
    const float m = msg[i];
    const float4* wrow = (const float4*)&W1s[i * 64 + q * 16];
#pragma unroll
    for (int j4 = 0; j4 < 4; ++j4) {
      float4 w = wrow[j4];
      acc[j4 * 4 + 0] += m * w.x;
      acc[j4 * 4 + 1] += m * w.y;
      acc[j4 * 4 + 2] += m * w.z;
      acc[j4 * 4 + 3] += m * w.w;
    }
  }
#pragma unroll
  for (int h = 0; h < 16; ++h) h1s[k][q * 16 + h] = fmaxf(acc[h], 0.0f);
  __syncthreads();

  const int ch = tid & 127, half = tid >> 7;
  float w2r[64];
#pragma unroll
  for (int i = 0; i < 64; ++i) w2r[i] = W2s[i * 128 + ch];

  float mx = -INFINITY;
  for (int k2 = half * 32; k2 < half * 32 + 32; ++k2) {
    if (!validk[k2]) continue;
    float s = b2s[ch];
    const float4* hr = (const float4*)h1s[k2];
#pragma unroll
    for (int i4 = 0; i4 < 16; ++i4) {
      float4 h4 = hr[i4];
      s += h4.x * w2r[i4 * 4 + 0] + h4.y * w2r[i4 * 4 + 1]
         + h4.z * w2r[i4 * 4 + 2] + h4.w * w2r[i4 * 4 + 3];
    }
    mx = fmaxf(mx, s);
  }
  pmax[half][ch] = mx;
  __syncthreads();

  if (tid < 128) {
    float m2 = fmaxf(pmax[0][tid], pmax[1][tid]);
    out[(size_t)c * CODIM + tid] = (m2 > -INFINITY) ? m2 : 0.0f;
  }
}

extern "C" void kernel_launch(void* const* d_in, const int* in_sizes, int n_in,
                              void* d_out, int out_size, void* d_ws, size_t ws_size,
                              hipStream_t stream) {
  const float* x   = (const float*)d_in[0];
  const float* pos = (const float*)d_in[1];
  const float* W1  = (const float*)d_in[3];
  const float* b1  = (const float*)d_in[4];
  const float* W2  = (const float*)d_in[5];
  const float* b2  = (const float*)d_in[6];
  float* out = (float*)d_out;

  int* fps_idx = (int*)d_ws;                  // B*M ints = 32 KiB
  int* nbr     = (int*)d_ws + BCLD * MCENT;   // B*M*K ints = 2 MiB
  // fps scratch aliases the nbr region (fps completes before ballq writes nbr)
  float4* ws_sorted = (float4*)nbr;           // B*N float4 = 512 KiB

  float* out_pc    = out + (size_t)BCLD * MCENT * CODIM;
  float* out_batch = out_pc + (size_t)BCLD * MCENT * 3;

  hipLaunchKernelGGL(fps_kernel, dim3(BCLD), dim3(1024), 0, stream, pos, fps_idx, ws_sorted);
  hipLaunchKernelGGL(ballq_kernel, dim3(BCLD * MCENT / 4), dim3(256), 0, stream,
                     pos, fps_idx, nbr, out_pc, out_batch);
  hipLaunchKernelGGL(mlp_kernel, dim3(BCLD * MCENT), dim3(256), 0, stream,
                     pos, x, fps_idx, nbr, W1, b1, W2, b2, out);
}

// Round 4
// 7661.434 us; speedup vs baseline: 1.8249x; 1.0741x over previous
//
#include <hip/hip_runtime.h>
#include <hip/hip_bf16.h>

#define NPTS 16384
#define MCENT 4096
#define BCLD 2
#define FDIM 32
#define H1DIM 64
#define CODIM 128
#define KNBR 64
// largest fp32 <= 0.04 (float64) == fp32(0.04f) == 0.039999999105930328
#define R2CUT 0.04f

// Exact (numpy-order, contraction-free) squared distance: ((dx*dx+dy*dy)+dz*dz)
__device__ __forceinline__ float d2e(float ax, float ay, float az,
                                     float bx, float by, float bz) {
  float dx = __fsub_rn(ax, bx);
  float dy = __fsub_rn(ay, by);
  float dz = __fsub_rn(az, bz);
  return __fadd_rn(__fadd_rn(__fmul_rn(dx, dx), __fmul_rn(dy, dy)), __fmul_rn(dz, dz));
}

// 3-bit spread for 9-bit Morton: b2 b1 b0 -> b2 _ _ b1 _ _ b0 (bits 6,3,0)
__device__ __forceinline__ int spread3(int v) {
  return ((v & 4) << 4) | ((v & 2) << 2) | (v & 1);
}
__device__ __forceinline__ int cell_of(float x, float y, float z) {
  int cx = min(7, (int)(x * 8.0f));
  int cy = min(7, (int)(y * 8.0f));
  int cz = min(7, (int)(z * 8.0f));
  // Morton order: a spatial ball maps to few contiguous cell ranges
  return (spread3(cx) << 2) | (spread3(cy) << 1) | spread3(cz);
}

// Lexicographic max over (bits, nidx) pairs via DPP (VALU pipe — no LDS).
// Identity (0,0) can never beat a real candidate (real nidx = ~oidx > 0).
#define DPP_LEXMAX_STEP(bb, nn, ctrl)                                          \
  do {                                                                         \
    unsigned _ob = (unsigned)__builtin_amdgcn_update_dpp(0, (int)(bb), ctrl,   \
                                                         0xf, 0xf, false);     \
    unsigned _on = (unsigned)__builtin_amdgcn_update_dpp(0, (int)(nn), ctrl,   \
                                                         0xf, 0xf, false);     \
    bool _t = (_ob > (bb)) || (_ob == (bb) && _on > (nn));                     \
    (bb) = _t ? _ob : (bb);                                                    \
    (nn) = _t ? _on : (nn);                                                    \
  } while (0)

__device__ __forceinline__ int rdlane(int v, int l) {
  return __builtin_amdgcn_readlane(v, l);
}
__device__ __forceinline__ float rdlanef(float v, int l) {
  return __int_as_float(__builtin_amdgcn_readlane(__float_as_int(v), l));
}

// ---------------- Kernel 1: farthest point sampling (1 block per cloud) ----
// 1024 threads x 16 pts, counting-sorted by MORTON cell id (8x8x8) so a dirty
// ball maps to few contiguous thread ranges (few dirty waves). Per-chunk bbox
// prune (0.999 margin >> fp rounding) skips provably-unchanged chunks. DPP
// lexmax reductions; 16 parity-double-buffered LDS slots (key b64 + pos b128);
// ONE barrier/iter; winners buffered in LDS, dumped once at the end.
__global__ __launch_bounds__(1024) void fps_kernel(const float* __restrict__ pos,
                                                   int* __restrict__ fps_idx,
                                                   float4* __restrict__ ws_sorted) {
  const int b = blockIdx.x;
  const float* P = pos + (size_t)b * NPTS * 3;
  float4* S = ws_sorted + (size_t)b * NPTS;
  const int tid = threadIdx.x;
  const int lane = tid & 63;
  const int wave = tid >> 6;  // 0..15

  __shared__ int hist[512];
  __shared__ int offs[512];
  __shared__ unsigned long long skey[2][16];
  __shared__ float4 spos[2][16];
  __shared__ int winners[MCENT];

  // ---- phase A: counting sort by Morton cell into ws_sorted (global) ----
  if (tid < 512) hist[tid] = 0;
  __syncthreads();
#pragma unroll 4
  for (int j = 0; j < 16; ++j) {
    int i = tid + j * 1024;
    float x = P[3 * i + 0], y = P[3 * i + 1], z = P[3 * i + 2];
    atomicAdd(&hist[cell_of(x, y, z)], 1);
  }
  __syncthreads();
  if (tid < 64) {  // wave 0: exclusive scan of 512 cells
    int base = tid * 8;
    int loc[8];
    int run = 0;
#pragma unroll
    for (int k = 0; k < 8; ++k) { loc[k] = run; run += hist[base + k]; }
    int inc = run;
#pragma unroll
    for (int off = 1; off < 64; off <<= 1) {
      int o = __shfl_up(inc, off);
      if (tid >= off) inc += o;
    }
    int ex = inc - run;
#pragma unroll
    for (int k = 0; k < 8; ++k) offs[base + k] = ex + loc[k];
  }
  __syncthreads();
#pragma unroll 4
  for (int j = 0; j < 16; ++j) {
    int i = tid + j * 1024;
    float x = P[3 * i + 0], y = P[3 * i + 1], z = P[3 * i + 2];
    int p = atomicAdd(&offs[cell_of(x, y, z)], 1);
    S[p] = make_float4(x, y, z, __int_as_float(i));
  }
  __syncthreads();  // global S writes drained before re-read (validated in R2)

  // ---- phase B: load 16-pt chunk, init d vs original point 0, bbox, best ----
  float px[16], py[16], pz[16], d[16];
  unsigned nidx[16];  // ~original_index (tiebreak payload, precomputed)
  const float x0 = P[0], y0 = P[1], z0 = P[2];
  float bxm, bxM, bym, byM, bzm, bzM;
  unsigned tb = 0u, tn = 0u;           // thread-best (d bits, ~oidx)
  float tx = 0.f, ty = 0.f, tz = 0.f;  // thread-best position
#pragma unroll
  for (int j = 0; j < 16; ++j) {
    float4 v = S[tid * 16 + j];
    px[j] = v.x; py[j] = v.y; pz[j] = v.z;
    nidx[j] = ~(unsigned)__float_as_int(v.w);
    float dj = d2e(v.x, v.y, v.z, x0, y0, z0);
    d[j] = dj;
    if (j == 0) {
      bxm = v.x; bxM = v.x; bym = v.y; byM = v.y; bzm = v.z; bzM = v.z;
    } else {
      bxm = fminf(bxm, v.x); bxM = fmaxf(bxM, v.x);
      bym = fminf(bym, v.y); byM = fmaxf(byM, v.y);
      bzm = fminf(bzm, v.z); bzM = fmaxf(bzM, v.z);
    }
    unsigned db = __float_as_uint(dj);
    unsigned nj = nidx[j];
    bool t = (db > tb) || (db == tb && nj > tn);
    tb = t ? db : tb; tn = t ? nj : tn;
    tx = t ? v.x : tx; ty = t ? v.y : ty; tz = t ? v.z : tz;
  }

  if (tid == 0) winners[0] = 0;

  bool wavedirty = true;
  unsigned cwb = 0u, cwn = 0u;           // cached wave-winner key
  float cwx = 0.f, cwy = 0.f, cwz = 0.f; // cached wave-winner pos

  for (int m = 1; m < MCENT; ++m) {
    const int par = m & 1;

    if (wavedirty) {  // recompute wave winner via full-wave DPP lexmax
      unsigned bb = tb, nn = tn;
      DPP_LEXMAX_STEP(bb, nn, 0x111);  // row_shr:1
      DPP_LEXMAX_STEP(bb, nn, 0x112);  // row_shr:2
      DPP_LEXMAX_STEP(bb, nn, 0x114);  // row_shr:4
      DPP_LEXMAX_STEP(bb, nn, 0x118);  // row_shr:8
      DPP_LEXMAX_STEP(bb, nn, 0x142);  // row_bcast:15
      DPP_LEXMAX_STEP(bb, nn, 0x143);  // row_bcast:31
      cwb = (unsigned)rdlane((int)bb, 63);
      cwn = (unsigned)rdlane((int)nn, 63);
      unsigned long long own = __ballot(tb == cwb && tn == cwn);
      int ol = (int)__ffsll(own) - 1;  // unique: nidx carries a unique point id
      cwx = rdlanef(tx, ol);
      cwy = rdlanef(ty, ol);
      cwz = rdlanef(tz, ol);
    }
    if (lane == 0) {  // always republish (parity buffer alternates)
      skey[par][wave] = ((unsigned long long)cwb << 32) | (unsigned long long)cwn;
      spos[par][wave] = make_float4(cwx, cwy, cwz, 0.0f);
    }
    __syncthreads();  // only lgkm traffic pending — cheap drain

    // cross-wave reduce: lanes 0..15 each take one slot, 4-step DPP lexmax
    unsigned rb, rn;
    unsigned sb0 = 0u, sn0 = 0u;
    {
      unsigned bb = 0u, nn = 0u;
      if (lane < 16) {
        unsigned long long kk = skey[par][lane];
        bb = (unsigned)(kk >> 32);
        nn = (unsigned)kk;
        sb0 = bb; sn0 = nn;
        DPP_LEXMAX_STEP(bb, nn, 0x111);
        DPP_LEXMAX_STEP(bb, nn, 0x112);
        DPP_LEXMAX_STEP(bb, nn, 0x114);
        DPP_LEXMAX_STEP(bb, nn, 0x118);
      }
      rb = (unsigned)rdlane((int)bb, 15);
      rn = (unsigned)rdlane((int)nn, 15);
    }
    unsigned long long wm = __ballot(lane < 16 && sb0 == rb && sn0 == rn);
    int ws = (int)__ffsll(wm) - 1;   // winning slot (wave) id — unique key
    float4 wp = spos[par][ws];       // single b128 broadcast read
    if (tid == 0) winners[m] = (int)(~rn);

    // prune: lower-bound distance from winner to chunk bbox
    float ex = fmaxf(fmaxf(bxm - wp.x, wp.x - bxM), 0.0f);
    float ey = fmaxf(fmaxf(bym - wp.y, wp.y - byM), 0.0f);
    float ez = fmaxf(fmaxf(bzm - wp.z, wp.z - bzM), 0.0f);
    float lb = (ex * ex + ey * ey + ez * ez) * 0.999f;
    bool mydirty = lb < __uint_as_float(tb);
    if (mydirty) {
      unsigned nb = 0u, nn2 = 0u;
      float nx = 0.f, ny = 0.f, nz = 0.f;
#pragma unroll
      for (int j = 0; j < 16; ++j) {
        float dj = fminf(d[j], d2e(px[j], py[j], pz[j], wp.x, wp.y, wp.z));
        d[j] = dj;
        unsigned db = __float_as_uint(dj);
        unsigned nj = nidx[j];
        bool t = (db > nb) || (db == nb && nj > nn2);
        nb = t ? db : nb; nn2 = t ? nj : nn2;
        nx = t ? px[j] : nx; ny = t ? py[j] : ny; nz = t ? pz[j] : nz;
      }
      tb = nb; tn = nn2; tx = nx; ty = ny; tz = nz;
    }
    wavedirty = (__ballot(mydirty) != 0ULL);
  }

  __syncthreads();
  for (int i = tid; i < MCENT; i += 1024) fps_idx[b * MCENT + i] = winners[i];
}

// ------------- Kernel 2: ball query + K-smallest selection (1 wave/centroid) --
__global__ __launch_bounds__(256) void ballq_kernel(const float* __restrict__ pos,
                                                    const int* __restrict__ fps_idx,
                                                    int* __restrict__ nbr,
                                                    float* __restrict__ out_pc,
                                                    float* __restrict__ out_batch) {
  const int wave = threadIdx.x >> 6;
  const int lane = threadIdx.x & 63;
  const int c = blockIdx.x * 4 + wave;   // global centroid id
  const int b = c >> 12;                 // 4096 centroids per cloud
  const float* P = pos + (size_t)b * NPTS * 3;

  const int ci = fps_idx[c];
  const float cx = P[3 * ci + 0];
  const float cy = P[3 * ci + 1];
  const float cz = P[3 * ci + 2];
  if (lane == 0) {
    out_pc[3 * c + 0] = cx;
    out_pc[3 * c + 1] = cy;
    out_pc[3 * c + 2] = cz;
    out_batch[c] = (float)b;
  }

  __shared__ unsigned long long list[4][1024];
  __shared__ int cnt[4];
  if (lane == 0) cnt[wave] = 0;

  for (int i = lane; i < NPTS; i += 64) {
    const float qx = P[3 * i + 0];
    const float qy = P[3 * i + 1];
    const float qz = P[3 * i + 2];
    const float dd = d2e(cx, cy, cz, qx, qy, qz);
    if (dd <= R2CUT) {
      int p = atomicAdd(&cnt[wave], 1);
      if (p < 1024)
        list[wave][p] = ((unsigned long long)__float_as_uint(dd) << 32)
                      | (unsigned long long)(unsigned)i;
    }
  }
  __syncthreads();

  int n = cnt[wave];
  if (n > 1024) n = 1024;

  unsigned long long loc[16];
#pragma unroll
  for (int k = 0; k < 16; ++k) {
    int i = lane + k * 64;
    loc[k] = (i < n) ? list[wave][i] : ~0ULL;
  }
  unsigned long long mv = loc[0];
#pragma unroll
  for (int k = 1; k < 16; ++k)
    if (loc[k] < mv) mv = loc[k];

  int myout = -1;
  for (int s = 0; s < 64; ++s) {
    unsigned long long wmin = mv;
#pragma unroll
    for (int off = 32; off >= 1; off >>= 1) {
      unsigned long long o = __shfl_xor(wmin, off);
      if (o < wmin) wmin = o;
    }
    if (lane == s) myout = (wmin == ~0ULL) ? -1 : (int)(unsigned)wmin;
    if (mv == wmin && wmin != ~0ULL) {
#pragma unroll
      for (int k = 0; k < 16; ++k)
        if (loc[k] == wmin) loc[k] = ~0ULL;
      mv = loc[0];
#pragma unroll
      for (int k = 1; k < 16; ++k)
        if (loc[k] < mv) mv = loc[k];
    }
  }
  nbr[c * KNBR + lane] = myout;
}

// ------------- Kernel 3: MLP (35->64 relu ->128) + masked max-pool ----------
__global__ __launch_bounds__(256) void mlp_kernel(const float* __restrict__ pos,
                                                  const float* __restrict__ x,
                                                  const int* __restrict__ fps_idx,
                                                  const int* __restrict__ nbr,
                                                  const float* __restrict__ W1,
                                                  const float* __restrict__ b1,
                                                  const float* __restrict__ W2,
                                                  const float* __restrict__ b2,
                                                  float* __restrict__ out) {
  const int c = blockIdx.x;
  const int b = c >> 12;
  const float* P = pos + (size_t)b * NPTS * 3;
  const float* X = x + (size_t)b * NPTS * FDIM;

  __shared__ float W1s[35 * 64];
  __shared__ float W2s[64 * 128];
  __shared__ float b1s[64];
  __shared__ float b2s[128];
  __shared__ float h1s[64][64];
  __shared__ float pmax[2][128];
  __shared__ int validk[64];

  const int tid = threadIdx.x;
  for (int i = tid; i < 35 * 64; i += 256) W1s[i] = W1[i];
  for (int i = tid; i < 64 * 128; i += 256) W2s[i] = W2[i];
  if (tid < 64) b1s[tid] = b1[tid];
  else if (tid < 192) b2s[tid - 64] = b2[tid - 64];

  const int ci = fps_idx[c];
  const float c5x = P[3 * ci + 0] / 0.2f;  // faithful: pos_i / r
  const float c5y = P[3 * ci + 1] / 0.2f;
  const float c5z = P[3 * ci + 2] / 0.2f;

  const int k = tid >> 2, q = tid & 3;
  const int nk = nbr[c * KNBR + k];
  if (q == 0) validk[k] = (nk >= 0) ? 1 : 0;
  const int nkc = (nk < 0) ? 0 : nk;

  float msg[35];
  const float4* Xr = (const float4*)(X + (size_t)nkc * FDIM);
#pragma unroll
  for (int i4 = 0; i4 < 8; ++i4) {
    float4 v = Xr[i4];
    msg[i4 * 4 + 0] = v.x; msg[i4 * 4 + 1] = v.y;
    msg[i4 * 4 + 2] = v.z; msg[i4 * 4 + 3] = v.w;
  }
  msg[32] = P[3 * nkc + 0] - c5x;
  msg[33] = P[3 * nkc + 1] - c5y;
  msg[34] = P[3 * nkc + 2] - c5z;

  __syncthreads();

  float acc[16];
#pragma unroll
  for (int h = 0; h < 16; ++h) acc[h] = b1s[q * 16 + h];
#pragma unroll
  for (int i = 0; i < 35; ++i) {
    const float m = msg[i];
    const float4* wrow = (const float4*)&W1s[i * 64 + q * 16];
#pragma unroll
    for (int j4 = 0; j4 < 4; ++j4) {
      float4 w = wrow[j4];
      acc[j4 * 4 + 0] += m * w.x;
      acc[j4 * 4 + 1] += m * w.y;
      acc[j4 * 4 + 2] += m * w.z;
      acc[j4 * 4 + 3] += m * w.w;
    }
  }
#pragma unroll
  for (int h = 0; h < 16; ++h) h1s[k][q * 16 + h] = fmaxf(acc[h], 0.0f);
  __syncthreads();

  const int ch = tid & 127, half = tid >> 7;
  float w2r[64];
#pragma unroll
  for (int i = 0; i < 64; ++i) w2r[i] = W2s[i * 128 + ch];

  float mx = -INFINITY;
  for (int k2 = half * 32; k2 < half * 32 + 32; ++k2) {
    if (!validk[k2]) continue;
    float s = b2s[ch];
    const float4* hr = (const float4*)h1s[k2];
#pragma unroll
    for (int i4 = 0; i4 < 16; ++i4) {
      float4 h4 = hr[i4];
      s += h4.x * w2r[i4 * 4 + 0] + h4.y * w2r[i4 * 4 + 1]
         + h4.z * w2r[i4 * 4 + 2] + h4.w * w2r[i4 * 4 + 3];
    }
    mx = fmaxf(mx, s);
  }
  pmax[half][ch] = mx;
  __syncthreads();

  if (tid < 128) {
    float m2 = fmaxf(pmax[0][tid], pmax[1][tid]);
    out[(size_t)c * CODIM + tid] = (m2 > -INFINITY) ? m2 : 0.0f;
  }
}

extern "C" void kernel_launch(void* const* d_in, const int* in_sizes, int n_in,
                              void* d_out, int out_size, void* d_ws, size_t ws_size,
                              hipStream_t stream) {
  const float* x   = (const float*)d_in[0];
  const float* pos = (const float*)d_in[1];
  const float* W1  = (const float*)d_in[3];
  const float* b1  = (const float*)d_in[4];
  const float* W2  = (const float*)d_in[5];
  const float* b2  = (const float*)d_in[6];
  float* out = (float*)d_out;

  int* fps_idx = (int*)d_ws;                  // B*M ints = 32 KiB
  int* nbr     = (int*)d_ws + BCLD * MCENT;   // B*M*K ints = 2 MiB
  // fps scratch aliases the nbr region (fps completes before ballq writes nbr)
  float4* ws_sorted = (float4*)nbr;           // B*N float4 = 512 KiB

  float* out_pc    = out + (size_t)BCLD * MCENT * CODIM;
  float* out_batch = out_pc + (size_t)BCLD * MCENT * 3;

  hipLaunchKernelGGL(fps_kernel, dim3(BCLD), dim3(1024), 0, stream, pos, fps_idx, ws_sorted);
  hipLaunchKernelGGL(ballq_kernel, dim3(BCLD * MCENT / 4), dim3(256), 0, stream,
                     pos, fps_idx, nbr, out_pc, out_batch);
  hipLaunchKernelGGL(mlp_kernel, dim3(BCLD * MCENT), dim3(256), 0, stream,
                     pos, x, fps_idx, nbr, W1, b1, W2, b2, out);
}